// Round 5
// baseline (306.568 us; speedup 1.0000x reference)
//
#include <hip/hip_runtime.h>

// ---------------------------------------------------------------------------
// CausalCrossAttention — pure-f16 MFMA pipeline, round 4 (resubmit; round-4
// bench was an infra timeout, kernel never measured)
// B=2 C=512 T=16 H=W=32 (P=16384/batch), S=64 D=1024, groups=32.
// Round-4 change: GEMM LDS staging in FRAGMENT ORDER (srow=lane&15,
// schunk=(lane>>4)*8) so every ds_read_b128 is a linear conflict-free
// 1KB stretch (was 8-way bank conflict, 2.1M conflict cycles/dispatch).
// ---------------------------------------------------------------------------

typedef float    f32x4 __attribute__((ext_vector_type(4)));
typedef _Float16 half8 __attribute__((ext_vector_type(8)));
typedef _Float16 half4 __attribute__((ext_vector_type(4)));

#define GLB_AS __attribute__((address_space(1)))
#define LDS_AS __attribute__((address_space(3)))

__device__ __forceinline__ void gload_lds16(const void* g, void* l) {
  __builtin_amdgcn_global_load_lds((const GLB_AS void*)g, (LDS_AS void*)l, 16, 0, 0);
}

// ---------------------------------------------------------------------------
// 1) Fused GroupNorm: block = (b, g, t) owns 16 ch x 1024 px (64 KB).
// ---------------------------------------------------------------------------
__global__ __launch_bounds__(256) void gn_fused(const float* __restrict__ x,
                                                const float* __restrict__ gamma,
                                                const float* __restrict__ beta,
                                                _Float16* __restrict__ h)
{
  const int t = blockIdx.x, g = blockIdx.y, b = blockIdx.z;
  const int tid = threadIdx.x;
  __shared__ float tile[16 * 1028];
  __shared__ float red[2][4];
  const long xbase = ((long)((b * 512 + g * 16) * 16 + t)) << 10;

  float s1 = 0.f, s2 = 0.f;
#pragma unroll
  for (int i = 0; i < 16; ++i) {
    const int idx = i * 256 + tid;
    const int c = idx >> 8;
    const int p = (idx & 255) * 4;
    const f32x4 v = *(const f32x4*)&x[xbase + ((long)c << 14) + p];
    s1 += v[0] + v[1] + v[2] + v[3];
    s2 += v[0] * v[0] + v[1] * v[1] + v[2] * v[2] + v[3] * v[3];
    *(f32x4*)&tile[c * 1028 + p] = v;
  }
  for (int o = 32; o; o >>= 1) { s1 += __shfl_down(s1, o); s2 += __shfl_down(s2, o); }
  if ((tid & 63) == 0) { red[0][tid >> 6] = s1; red[1][tid >> 6] = s2; }
  __syncthreads();
  const float a  = red[0][0] + red[0][1] + red[0][2] + red[0][3];
  const float qq = red[1][0] + red[1][1] + red[1][2] + red[1][3];
  const float mu = a * (1.f / 16384.f);
  const float rs = rsqrtf(qq * (1.f / 16384.f) - mu * mu + 1e-5f);

  float scv[16], ocv[16];
#pragma unroll
  for (int c4 = 0; c4 < 4; ++c4) {
    const f32x4 gv = *(const f32x4*)&gamma[g * 16 + c4 * 4];
    const f32x4 bv = *(const f32x4*)&beta[g * 16 + c4 * 4];
#pragma unroll
    for (int j = 0; j < 4; ++j) {
      scv[c4 * 4 + j] = rs * gv[j];
      ocv[c4 * 4 + j] = bv[j] - mu * scv[c4 * 4 + j];
    }
  }

  const long hbase = (((long)b * 16384 + (long)t * 1024) << 9) + g * 16;
#pragma unroll
  for (int it = 0; it < 4; ++it) {
    const int p = it * 256 + tid;
    half8 h0, h1;
#pragma unroll
    for (int c = 0; c < 16; ++c) {
      const _Float16 hv = (_Float16)(tile[c * 1028 + p] * scv[c] + ocv[c]);
      if (c < 8) h0[c] = hv; else h1[c - 8] = hv;
    }
    *(half8*)&h[hbase + (long)p * 512]     = h0;
    *(half8*)&h[hbase + (long)p * 512 + 8] = h1;
  }
}

// ---------------------------------------------------------------------------
// 2) f32 -> f16 conversion (weights)
// ---------------------------------------------------------------------------
__global__ void to_f16(const float* __restrict__ src, _Float16* __restrict__ dst, int n4)
{
  const int i = blockIdx.x * blockDim.x + threadIdx.x;
  if (i >= n4) return;
  const f32x4 v = *(const f32x4*)&src[i * 4];
  half4 hh;
#pragma unroll
  for (int j = 0; j < 4; ++j) hh[j] = (_Float16)v[j];
  *(half4*)&dst[i * 4] = hh;
}

// ---------------------------------------------------------------------------
// 3) kv mini-GEMM: kv[b,s,o] = ctx[b,s,:].wkv[o,:] + bkv[o]
// ---------------------------------------------------------------------------
__global__ __launch_bounds__(256) void kv_gemm(const float* __restrict__ ctx,
                                               const float* __restrict__ wkv,
                                               const float* __restrict__ bkv,
                                               _Float16* __restrict__ kOut,
                                               _Float16* __restrict__ vT)
{
  const int b = blockIdx.y;
  const int o0 = blockIdx.x * 16;
  const int tid = threadIdx.x, l = tid & 63, w = tid >> 6;
  __shared__ float cbuf[64 * 64];   // ctx chunk [s][d], XOR-16B swizzled
  __shared__ float wbuf[16 * 64];   // wkv chunk [o][d], linear (broadcast reads)
  float acc[4] = {0.f, 0.f, 0.f, 0.f};

  for (int dc = 0; dc < 16; ++dc) {
#pragma unroll
    for (int i = 0; i < 4; ++i) {
      const int lin = tid + i * 256;
      const int s = lin >> 4, c4 = lin & 15;
      *(f32x4*)&cbuf[s * 64 + ((c4 ^ (s & 15)) << 2)] =
          *(const f32x4*)&ctx[((long)(b * 64 + s) << 10) + dc * 64 + c4 * 4];
    }
    {
      const int o = tid >> 4, c4 = tid & 15;
      *(f32x4*)&wbuf[o * 64 + c4 * 4] =
          *(const f32x4*)&wkv[((long)(o0 + o) << 10) + dc * 64 + c4 * 4];
    }
    __syncthreads();
#pragma unroll
    for (int d4 = 0; d4 < 16; ++d4) {
      const f32x4 cv = *(const f32x4*)&cbuf[l * 64 + ((d4 ^ (l & 15)) << 2)];
#pragma unroll
      for (int j = 0; j < 4; ++j) {
        const f32x4 wv = *(const f32x4*)&wbuf[(w * 4 + j) * 64 + (d4 << 2)];
        acc[j] += cv[0] * wv[0] + cv[1] * wv[1] + cv[2] * wv[2] + cv[3] * wv[3];
      }
    }
    __syncthreads();
  }
#pragma unroll
  for (int j = 0; j < 4; ++j) {
    const int o = o0 + w * 4 + j;
    const float r = acc[j] + bkv[o];
    if (o < 512) kOut[((long)(b * 64 + l) << 9) + o] = (_Float16)r;
    else         vT[((long)(b * 512 + (o - 512)) << 6) + l] = (_Float16)r;
  }
}

// ---------------------------------------------------------------------------
// 4) f16 TN GEMM, 2-phase prefetch, XCD swizzle, FRAGMENT-ORDER LDS staging.
//    LDS subtile s (16 rows x 32 k = 1KB) holds chunk l = (row l&15,
//    kslot l>>4); fragment read = subtile_base + lane*16 (conflict-free).
// ---------------------------------------------------------------------------
#define BM 128
#define BN 128
#define BK 32

template <int BIAS_PER_N, int RESID, int OUT16, int SWZ>
__global__ __launch_bounds__(256) void gemm_f16(
    const _Float16* __restrict__ A, const _Float16* __restrict__ B,
    void* __restrict__ Cv, const float* __restrict__ bias, const float* __restrict__ resid,
    int K, int lda, int ldb, int ldc,
    long aBatch, long bBatch, long cBatch, long rBatch)
{
  __shared__ _Float16 sA[2][BM * BK];
  __shared__ _Float16 sB[2][BN * BK];
  const int tid = threadIdx.x;
  const int lane = tid & 63;
  const int w = tid >> 6;
  const int bz = blockIdx.z;

  int bx, by;
  if (SWZ == 1) {        // 512 blocks: same-n m-group -> same XCD
    const int f = blockIdx.x;
    const int nf = ((f & 7) << 6) | (f >> 3);
    bx = nf & 3; by = nf >> 2;
  } else if (SWZ == 2) { // 512 blocks: same-m n-group -> same XCD
    const int f = blockIdx.x;
    const int nf = ((f & 7) << 6) | (f >> 3);
    bx = nf >> 2; by = nf & 3;
  } else {
    bx = blockIdx.x; by = blockIdx.y;
  }

  const long m0 = (long)bx * BM;
  const long n0 = (long)by * BN;
  const _Float16* pA = A + bz * aBatch + m0 * lda;
  const _Float16* pB = B + bz * bBatch + n0 * ldb;
  const int srow = lane & 15;            // fragment-order staging
  const int schunk = (lane >> 4) * 8;
  const int wm = w >> 1, wn = w & 1;

  f32x4 acc[4][4] = {};

  auto stage = [&](int buf, int k0) {
#pragma unroll
    for (int i = 0; i < 2; ++i) {
      const int r = w * 32 + i * 16 + srow;
      const int lbase = (w * 32 + i * 16) * BK;
      gload_lds16(pA + (long)r * lda + k0 + schunk, &sA[buf][lbase]);
      gload_lds16(pB + (long)r * ldb + k0 + schunk, &sB[buf][lbase]);
    }
  };

  stage(0, 0);
  __syncthreads();
  int cur = 0;
  for (int k0 = 0; k0 < K; k0 += BK) {
    if (k0 + BK < K) stage(cur ^ 1, k0 + BK);
    half8 ah[4], bh[4];
#pragma unroll
    for (int mi = 0; mi < 4; ++mi)
      ah[mi] = *(const half8*)&sA[cur][(wm * 4 + mi) * 512 + lane * 8];
#pragma unroll
    for (int ni = 0; ni < 4; ++ni)
      bh[ni] = *(const half8*)&sB[cur][(wn * 4 + ni) * 512 + lane * 8];
#pragma unroll
    for (int mi = 0; mi < 4; ++mi)
#pragma unroll
      for (int ni = 0; ni < 4; ++ni)
        acc[mi][ni] = __builtin_amdgcn_mfma_f32_16x16x32_f16(ah[mi], bh[ni], acc[mi][ni], 0, 0, 0);
    __syncthreads();
    cur ^= 1;
  }

  const long cb = bz * cBatch;
  const long rb = bz * rBatch;
#pragma unroll
  for (int mi = 0; mi < 4; ++mi) {
#pragma unroll
    for (int ni = 0; ni < 4; ++ni) {
      const long row = m0 + wm * 64 + mi * 16 + (lane >> 4) * 4;
      const long col = n0 + wn * 64 + ni * 16 + (lane & 15);
#pragma unroll
      for (int j = 0; j < 4; ++j) {
        float v = acc[mi][ni][j];
        v += BIAS_PER_N ? bias[col] : bias[row + j];
        if (RESID) v += resid[rb + (row + j) * ldc + col];
        if (OUT16) ((_Float16*)Cv)[cb + (row + j) * ldc + col] = (_Float16)v;
        else       ((float*)Cv)[cb + (row + j) * ldc + col] = v;
      }
    }
  }
}

// ---------------------------------------------------------------------------
// 5) Barrier-free MFMA attention (unchanged).
// ---------------------------------------------------------------------------
__global__ __launch_bounds__(256) void attn2(const _Float16* __restrict__ q,   // [b][p][c]
                                             const _Float16* __restrict__ k,   // [b][s][c]
                                             const _Float16* __restrict__ vT,  // [b][c][s]
                                             _Float16* __restrict__ O)         // [b][p][c]
{
  const int tid = threadIdx.x;
  const int l = tid & 63, w = tid >> 6;
  const int b = blockIdx.z, t = blockIdx.y;
  const int p0 = t * 1024 + blockIdx.x * 64 + w * 16;
  const int lim = (t + 1) * 4;
  const int nf = (t >> 2) + 1;
  const int ks = (t >> 3) + 1;
  const int cl = l & 15;
  const int g8 = (l >> 4) * 8;
  const int r4 = (l >> 4) * 4;

  __shared__ _Float16 wlds[4][16][72];

  f32x4 sc[4] = {};
  const _Float16* qb = q + (((long)(b * 16384 + p0 + cl)) << 9) + g8;
  const _Float16* kb = k + (((long)(b * 64 + cl)) << 9) + g8;
#pragma unroll
  for (int kk = 0; kk < 16; ++kk) {
    const half8 af = *(const half8*)(qb + kk * 32);
#pragma unroll
    for (int f = 0; f < 4; ++f)
      if (f < nf)
        sc[f] = __builtin_amdgcn_mfma_f32_16x16x32_f16(
            af, *(const half8*)(kb + f * (16 * 512) + kk * 32), sc[f], 0, 0, 0);
  }

  const float SCALE = 0.044194173824159216f;   // 1/sqrt(512)
  float ex[4][4], mj[4], sj[4];
#pragma unroll
  for (int j = 0; j < 4; ++j) {
    float mx = -1e30f;
#pragma unroll
    for (int f = 0; f < 4; ++f) {
      float v = sc[f][j] * SCALE;
      if (f * 16 + cl >= lim) v = -1e30f;
      ex[f][j] = v;
      mx = fmaxf(mx, v);
    }
    mj[j] = mx;
  }
#pragma unroll
  for (int o = 1; o < 16; o <<= 1)
#pragma unroll
    for (int j = 0; j < 4; ++j) mj[j] = fmaxf(mj[j], __shfl_xor(mj[j], o));
#pragma unroll
  for (int j = 0; j < 4; ++j) {
    float s = 0.f;
#pragma unroll
    for (int f = 0; f < 4; ++f) {
      const float e = __expf(ex[f][j] - mj[j]);
      ex[f][j] = e;
      s += e;
    }
    sj[j] = s;
  }
#pragma unroll
  for (int o = 1; o < 16; o <<= 1)
#pragma unroll
    for (int j = 0; j < 4; ++j) sj[j] += __shfl_xor(sj[j], o);
#pragma unroll
  for (int j = 0; j < 4; ++j) {
    const float inv = 1.f / sj[j];
#pragma unroll
    for (int f = 0; f < 4; ++f)
      wlds[w][r4 + j][f * 16 + cl] = (_Float16)(ex[f][j] * inv);
  }

  const half8 wa0 = *(const half8*)&wlds[w][cl][g8];
  const half8 wa1 = *(const half8*)&wlds[w][cl][32 + g8];
#pragma unroll
  for (int hf = 0; hf < 2; ++hf) {
    f32x4 oc[16] = {};
#pragma unroll
    for (int cf = 0; cf < 16; ++cf) {
      const _Float16* vb = vT + (((long)(b * 512 + hf * 256 + cf * 16 + cl)) << 6) + g8;
      oc[cf] = __builtin_amdgcn_mfma_f32_16x16x32_f16(wa0, *(const half8*)vb, oc[cf], 0, 0, 0);
      if (ks == 2)
        oc[cf] = __builtin_amdgcn_mfma_f32_16x16x32_f16(wa1, *(const half8*)(vb + 32), oc[cf], 0, 0, 0);
    }
#pragma unroll
    for (int cf = 0; cf < 16; ++cf)
#pragma unroll
      for (int j = 0; j < 4; ++j)
        O[(((long)(b * 16384 + p0 + r4 + j)) << 9) + hf * 256 + cf * 16 + cl] =
            (_Float16)oc[cf][j];
  }
}

// ---------------------------------------------------------------------------
// launcher
// ---------------------------------------------------------------------------
extern "C" void kernel_launch(void* const* d_in, const int* in_sizes, int n_in,
                              void* d_out, int out_size, void* d_ws, size_t ws_size,
                              hipStream_t stream)
{
  (void)in_sizes; (void)n_in; (void)out_size; (void)ws_size;
  const float* x     = (const float*)d_in[0];
  const float* ctx   = (const float*)d_in[1];
  const float* gamma = (const float*)d_in[2];
  const float* beta  = (const float*)d_in[3];
  const float* wq    = (const float*)d_in[4];
  const float* bq    = (const float*)d_in[5];
  const float* wkv   = (const float*)d_in[6];
  const float* bkv   = (const float*)d_in[7];
  const float* wo    = (const float*)d_in[8];
  const float* bo    = (const float*)d_in[9];
  float* out = (float*)d_out;

  char* ws = (char*)d_ws;
  size_t off = 0;
  auto alloc = [&](size_t bytes) -> void* {
    void* p = ws + off;
    off += (bytes + 255) & ~(size_t)255;
    return p;
  };
  const long HPC = 8388608;                        // 16384*512 per batch
  _Float16* hF   = (_Float16*)alloc(2 * HPC * 2);  // h [b][p][c] f16 (reused for O)
  _Float16* qF   = (_Float16*)alloc(2 * HPC * 2);  // q [b][p][c] f16
  _Float16* wqF  = (_Float16*)alloc(512 * 512 * 2);
  _Float16* woF  = (_Float16*)alloc(512 * 512 * 2);
  _Float16* kF   = (_Float16*)alloc(2 * 64 * 512 * 2);   // k [b][s][c]
  _Float16* vTF  = (_Float16*)alloc(2 * 512 * 64 * 2);   // vT [b][c][s]
  _Float16* oF   = hF;                             // h dead after q-GEMM

  gn_fused<<<dim3(16, 32, 2), 256, 0, stream>>>(x, gamma, beta, hF);
  to_f16<<<dim3(256), 256, 0, stream>>>(wq, wqF, 65536);
  to_f16<<<dim3(256), 256, 0, stream>>>(wo, woF, 65536);
  kv_gemm<<<dim3(64, 2), 256, 0, stream>>>(ctx, wkv, bkv, kF, vTF);

  // q[b][p][o] = h[b][p][:].wq[o][:] + bq[o]  (f16 out; swz mode 2)
  gemm_f16<1, 0, 1, 2><<<dim3(512, 1, 2), 256, 0, stream>>>(
      hF, wqF, qF, bq, nullptr, 512, 512, 512, 512, HPC, 0, HPC, 0);

  attn2<<<dim3(16, 16, 2), 256, 0, stream>>>(qF, kF, vTF, oF);

  // out[b][o][p] = x[b][o][p] + O[b][p][:].wo[o][:] + bo[o]  (f32 out; swz mode 1)
  gemm_f16<0, 1, 0, 1><<<dim3(512, 1, 2), 256, 0, stream>>>(
      woF, oF, out, bo, x, 512, 512, 512, 16384, 0, HPC, HPC, HPC);
}

// Round 6
// 306.370 us; speedup vs baseline: 1.0006x; 1.0006x over previous
//
#include <hip/hip_runtime.h>

// ---------------------------------------------------------------------------
// CausalCrossAttention — round 6: fused q-GEMM + attention + o-GEMM.
// B=2 C=512 T=16 H=W=32 (P=16384/batch), S=64 D=1024, groups=32.
// gn_fused(h f16) -> [wq,wo->f16] kv mini-GEMM(k,vT f16) -> fused_qao.
// fused_qao: block = (b, 128-row p-tile) (256 blocks = 1/CU), 512 thr.
//   q_ch = h.wq_ch (h LDS-staged w/ XOR swizzle; wq L2-direct) -> qbuf
//   scores += q_ch.k_ch^T ; softmax in-reg ; P -> pbuf
//   O_ch = P.V_ch -> qbuf ; out_acc += wo_ch.O_ch^T (K-split, 128 VGPR acc)
//   out = out_acc + bo + x residual.  No qF/oF round-trips.
// ---------------------------------------------------------------------------

typedef float    f32x4 __attribute__((ext_vector_type(4)));
typedef _Float16 half8 __attribute__((ext_vector_type(8)));
typedef _Float16 half4 __attribute__((ext_vector_type(4)));

#define GLB_AS __attribute__((address_space(1)))
#define LDS_AS __attribute__((address_space(3)))

__device__ __forceinline__ void gload_lds16(const void* g, void* l) {
  __builtin_amdgcn_global_load_lds((const GLB_AS void*)g, (LDS_AS void*)l, 16, 0, 0);
}

// ---------------------------------------------------------------------------
// 1) Fused GroupNorm: block = (b, g, t) owns 16 ch x 1024 px (64 KB).
// ---------------------------------------------------------------------------
__global__ __launch_bounds__(256) void gn_fused(const float* __restrict__ x,
                                                const float* __restrict__ gamma,
                                                const float* __restrict__ beta,
                                                _Float16* __restrict__ h)
{
  const int t = blockIdx.x, g = blockIdx.y, b = blockIdx.z;
  const int tid = threadIdx.x;
  __shared__ float tile[16 * 1028];
  __shared__ float red[2][4];
  const long xbase = ((long)((b * 512 + g * 16) * 16 + t)) << 10;

  float s1 = 0.f, s2 = 0.f;
#pragma unroll
  for (int i = 0; i < 16; ++i) {
    const int idx = i * 256 + tid;
    const int c = idx >> 8;
    const int p = (idx & 255) * 4;
    const f32x4 v = *(const f32x4*)&x[xbase + ((long)c << 14) + p];
    s1 += v[0] + v[1] + v[2] + v[3];
    s2 += v[0] * v[0] + v[1] * v[1] + v[2] * v[2] + v[3] * v[3];
    *(f32x4*)&tile[c * 1028 + p] = v;
  }
  for (int o = 32; o; o >>= 1) { s1 += __shfl_down(s1, o); s2 += __shfl_down(s2, o); }
  if ((tid & 63) == 0) { red[0][tid >> 6] = s1; red[1][tid >> 6] = s2; }
  __syncthreads();
  const float a  = red[0][0] + red[0][1] + red[0][2] + red[0][3];
  const float qq = red[1][0] + red[1][1] + red[1][2] + red[1][3];
  const float mu = a * (1.f / 16384.f);
  const float rs = rsqrtf(qq * (1.f / 16384.f) - mu * mu + 1e-5f);

  float scv[16], ocv[16];
#pragma unroll
  for (int c4 = 0; c4 < 4; ++c4) {
    const f32x4 gv = *(const f32x4*)&gamma[g * 16 + c4 * 4];
    const f32x4 bv = *(const f32x4*)&beta[g * 16 + c4 * 4];
#pragma unroll
    for (int j = 0; j < 4; ++j) {
      scv[c4 * 4 + j] = rs * gv[j];
      ocv[c4 * 4 + j] = bv[j] - mu * scv[c4 * 4 + j];
    }
  }

  const long hbase = (((long)b * 16384 + (long)t * 1024) << 9) + g * 16;
#pragma unroll
  for (int it = 0; it < 4; ++it) {
    const int p = it * 256 + tid;
    half8 h0, h1;
#pragma unroll
    for (int c = 0; c < 16; ++c) {
      const _Float16 hv = (_Float16)(tile[c * 1028 + p] * scv[c] + ocv[c]);
      if (c < 8) h0[c] = hv; else h1[c - 8] = hv;
    }
    *(half8*)&h[hbase + (long)p * 512]     = h0;
    *(half8*)&h[hbase + (long)p * 512 + 8] = h1;
  }
}

// ---------------------------------------------------------------------------
// 2) f32 -> f16 conversion (weights)
// ---------------------------------------------------------------------------
__global__ void to_f16(const float* __restrict__ src, _Float16* __restrict__ dst, int n4)
{
  const int i = blockIdx.x * blockDim.x + threadIdx.x;
  if (i >= n4) return;
  const f32x4 v = *(const f32x4*)&src[i * 4];
  half4 hh;
#pragma unroll
  for (int j = 0; j < 4; ++j) hh[j] = (_Float16)v[j];
  *(half4*)&dst[i * 4] = hh;
}

// ---------------------------------------------------------------------------
// 3) kv mini-GEMM: kv[b,s,o] = ctx[b,s,:].wkv[o,:] + bkv[o]
// ---------------------------------------------------------------------------
__global__ __launch_bounds__(256) void kv_gemm(const float* __restrict__ ctx,
                                               const float* __restrict__ wkv,
                                               const float* __restrict__ bkv,
                                               _Float16* __restrict__ kOut,
                                               _Float16* __restrict__ vT)
{
  const int b = blockIdx.y;
  const int o0 = blockIdx.x * 16;
  const int tid = threadIdx.x, l = tid & 63, w = tid >> 6;
  __shared__ float cbuf[64 * 64];
  __shared__ float wbuf[16 * 64];
  float acc[4] = {0.f, 0.f, 0.f, 0.f};

  for (int dc = 0; dc < 16; ++dc) {
#pragma unroll
    for (int i = 0; i < 4; ++i) {
      const int lin = tid + i * 256;
      const int s = lin >> 4, c4 = lin & 15;
      *(f32x4*)&cbuf[s * 64 + ((c4 ^ (s & 15)) << 2)] =
          *(const f32x4*)&ctx[((long)(b * 64 + s) << 10) + dc * 64 + c4 * 4];
    }
    {
      const int o = tid >> 4, c4 = tid & 15;
      *(f32x4*)&wbuf[o * 64 + c4 * 4] =
          *(const f32x4*)&wkv[((long)(o0 + o) << 10) + dc * 64 + c4 * 4];
    }
    __syncthreads();
#pragma unroll
    for (int d4 = 0; d4 < 16; ++d4) {
      const f32x4 cv = *(const f32x4*)&cbuf[l * 64 + ((d4 ^ (l & 15)) << 2)];
#pragma unroll
      for (int j = 0; j < 4; ++j) {
        const f32x4 wv = *(const f32x4*)&wbuf[(w * 4 + j) * 64 + (d4 << 2)];
        acc[j] += cv[0] * wv[0] + cv[1] * wv[1] + cv[2] * wv[2] + cv[3] * wv[3];
      }
    }
    __syncthreads();
  }
#pragma unroll
  for (int j = 0; j < 4; ++j) {
    const int o = o0 + w * 4 + j;
    const float r = acc[j] + bkv[o];
    if (o < 512) kOut[((long)(b * 64 + l) << 9) + o] = (_Float16)r;
    else         vT[((long)(b * 512 + (o - 512)) << 6) + l] = (_Float16)r;
  }
}

// ---------------------------------------------------------------------------
// 4) fused q-proj + attention + o-proj (+bias+residual)
// ---------------------------------------------------------------------------
__global__ __launch_bounds__(512) void fused_qao(
    const _Float16* __restrict__ h,    // [b][p][c] f16
    const _Float16* __restrict__ wq,   // [o][c] f16
    const float* __restrict__ bq,
    const _Float16* __restrict__ kM,   // [b][s][c] f16
    const _Float16* __restrict__ vT,   // [b][c][s] f16
    const _Float16* __restrict__ wo,   // [o][c] f16
    const float* __restrict__ bo,
    const float* __restrict__ xr,      // [b][o][p] f32 residual
    float* __restrict__ out)           // [b][o][p] f32
{
  const int tid = threadIdx.x;
  const int l = tid & 63, w = tid >> 6;
  const int b = blockIdx.y;
  const int p0 = blockIdx.x * 128;
  const int t = p0 >> 10;
  const int lim = (t + 1) * 4;           // valid context length
  const int nfc = (t >> 2) + 1;          // s-frags with any valid col
  const int ksc = (t >> 3) + 1;          // 32-wide s k-steps needed
  const int cl = l & 15, kc = l >> 4, r4 = (l >> 4) * 4;

  __shared__ _Float16 qbuf[128 * 256];     // 64KB: q_ch then O_ch (swizzled)
  __shared__ _Float16 hstage[2][128 * 32]; // 16KB: h k-tile double buffer
  __shared__ _Float16 pbuf[128 * 64];      // 16KB: softmax P (swizzled)

  const int swA = (cl >> 1) & 3;           // hstage read swizzle
  const int sw7 = cl & 7;                  // qbuf/pbuf read swizzle
  const int wm2 = w >> 2, wn4 = w & 3;     // phases 1a/3a: 2x4 waves (64 x 64)
  const int wm4 = w >> 1, wn2 = w & 1;     // phase 3b: 4x2 waves (128o x 64p)

  // h staging: coalesced rows (16w + l>>2), XOR-swizzled chunk (both sides)
  const int srow = 16 * w + (l >> 2);
  const int schunk = (l & 3) ^ ((l >> 3) & 3);
  const _Float16* hsrc = h + (((long)(b * 16384 + p0 + srow)) << 9) + schunk * 8;
  _Float16* hdst0 = &hstage[0][w * 512];
  _Float16* hdst1 = &hstage[1][w * 512];

  f32x4 acc_s[4] = {};                     // scores rows 16w+r4+j, col cl+16ni

  for (int ch = 0; ch < 2; ++ch) {
    // ---- 1a: q_ch[128p x 256o] = h . wq_ch^T ----
    f32x4 accq[4][4] = {};
    gload_lds16(hsrc, hdst0);
    __syncthreads();
    int cur = 0;
    for (int ks = 0; ks < 16; ++ks) {
      const int k0 = ks * 32;
      if (ks < 15) gload_lds16(hsrc + k0 + 32, cur ? hdst0 : hdst1);
      half8 ah[4], bh[4];
#pragma unroll
      for (int ni = 0; ni < 4; ++ni)
        bh[ni] = *(const half8*)&wq[((long)(ch * 256 + wn4 * 64 + ni * 16 + cl) << 9) + k0 + kc * 8];
#pragma unroll
      for (int mi = 0; mi < 4; ++mi)
        ah[mi] = *(const half8*)&hstage[cur][(wm2 * 64 + mi * 16 + cl) * 32 + ((kc ^ swA) * 8)];
#pragma unroll
      for (int mi = 0; mi < 4; ++mi)
#pragma unroll
        for (int ni = 0; ni < 4; ++ni)
          accq[mi][ni] = __builtin_amdgcn_mfma_f32_16x16x32_f16(ah[mi], bh[ni], accq[mi][ni], 0, 0, 0);
      __syncthreads();
      cur ^= 1;
    }
    // ---- 1b: q_ch (+bq) -> qbuf (XOR-swizzled) ----
#pragma unroll
    for (int mi = 0; mi < 4; ++mi) {
#pragma unroll
      for (int ni = 0; ni < 4; ++ni) {
        const int col = wn4 * 64 + ni * 16 + cl;
        const float bqv = bq[ch * 256 + col];
#pragma unroll
        for (int j = 0; j < 4; ++j) {
          const int row = wm2 * 64 + mi * 16 + r4 + j;
          qbuf[row * 256 + (((col >> 3) ^ (row & 7)) * 8) + (col & 7)] =
              (_Float16)(accq[mi][ni][j] + bqv);
        }
      }
    }
    __syncthreads();
    // ---- 1c: scores += q_ch . k_ch^T (wave w owns score rows 16w..+16) ----
    {
      const int qrow = 16 * w + cl;
#pragma unroll
      for (int ks = 0; ks < 8; ++ks) {
        const half8 af = *(const half8*)&qbuf[qrow * 256 + (((ks * 4 + kc) ^ sw7) * 8)];
#pragma unroll
        for (int ni = 0; ni < 4; ++ni)
          if (ni < nfc)
            acc_s[ni] = __builtin_amdgcn_mfma_f32_16x16x32_f16(
                af,
                *(const half8*)&kM[((long)(b * 64 + ni * 16 + cl) << 9) + ch * 256 + ks * 32 + kc * 8],
                acc_s[ni], 0, 0, 0);
      }
    }
    __syncthreads();
  }

  // ---- 2: softmax (reduce across the 16-lane col group) -> pbuf ----
  {
    const float SCALE = 0.044194173824159216f;   // 1/sqrt(512)
    float ex[4][4], mj[4], sj[4];
#pragma unroll
    for (int j = 0; j < 4; ++j) {
      float mx = -1e30f;
#pragma unroll
      for (int ni = 0; ni < 4; ++ni) {
        const float v = (ni * 16 + cl < lim) ? acc_s[ni][j] * SCALE : -1e30f;
        ex[ni][j] = v;
        mx = fmaxf(mx, v);
      }
      mj[j] = mx;
    }
#pragma unroll
    for (int o = 1; o < 16; o <<= 1)
#pragma unroll
      for (int j = 0; j < 4; ++j) mj[j] = fmaxf(mj[j], __shfl_xor(mj[j], o));
#pragma unroll
    for (int j = 0; j < 4; ++j) {
      float s = 0.f;
#pragma unroll
      for (int ni = 0; ni < 4; ++ni) {
        const float e = __expf(ex[ni][j] - mj[j]);   // masked -> 0
        ex[ni][j] = e;
        s += e;
      }
      sj[j] = s;
    }
#pragma unroll
    for (int o = 1; o < 16; o <<= 1)
#pragma unroll
      for (int j = 0; j < 4; ++j) sj[j] += __shfl_xor(sj[j], o);
#pragma unroll
    for (int j = 0; j < 4; ++j) {
      const float inv = 1.f / sj[j];
      const int row = 16 * w + r4 + j;
#pragma unroll
      for (int ni = 0; ni < 4; ++ni) {
        const int col = ni * 16 + cl;
        pbuf[row * 64 + (((col >> 3) ^ (row & 7)) * 8) + (col & 7)] =
            (_Float16)(ex[ni][j] * inv);
      }
    }
  }
  __syncthreads();

  // ---- 3: O_ch = P.V_ch -> qbuf ; out_acc += wo_ch . O_ch^T ----
  f32x4 acc_out[8][4] = {};
  for (int ch = 0; ch < 2; ++ch) {
    f32x4 acco[4][4] = {};
#pragma unroll
    for (int ks = 0; ks < 2; ++ks) {
      if (ks < ksc) {
        half8 af[4];
#pragma unroll
        for (int mi = 0; mi < 4; ++mi)
          af[mi] = *(const half8*)&pbuf[(wm2 * 64 + mi * 16 + cl) * 64 + (((ks * 4 + kc) ^ sw7) * 8)];
#pragma unroll
        for (int mi = 0; mi < 4; ++mi)
#pragma unroll
          for (int ni = 0; ni < 4; ++ni)
            acco[mi][ni] = __builtin_amdgcn_mfma_f32_16x16x32_f16(
                af[mi],
                *(const half8*)&vT[((long)(b * 512 + ch * 256 + wn4 * 64 + ni * 16 + cl) << 6) + ks * 32 + kc * 8],
                acco[mi][ni], 0, 0, 0);
      }
    }
#pragma unroll
    for (int mi = 0; mi < 4; ++mi) {
#pragma unroll
      for (int ni = 0; ni < 4; ++ni) {
        const int col = wn4 * 64 + ni * 16 + cl;
#pragma unroll
        for (int j = 0; j < 4; ++j) {
          const int row = wm2 * 64 + mi * 16 + r4 + j;
          qbuf[row * 256 + (((col >> 3) ^ (row & 7)) * 8) + (col & 7)] = (_Float16)acco[mi][ni][j];
        }
      }
    }
    __syncthreads();
    // 3b: out[512o x 128p] += wo[:, ch-half] . O_ch^T   (K=256)
#pragma unroll
    for (int ks = 0; ks < 8; ++ks) {
      half8 aw[8], bh[4];
#pragma unroll
      for (int mi = 0; mi < 8; ++mi)
        aw[mi] = *(const half8*)&wo[((long)(wm4 * 128 + mi * 16 + cl) << 9) + ch * 256 + ks * 32 + kc * 8];
#pragma unroll
      for (int ni = 0; ni < 4; ++ni)
        bh[ni] = *(const half8*)&qbuf[(wn2 * 64 + ni * 16 + cl) * 256 + (((ks * 4 + kc) ^ sw7) * 8)];
#pragma unroll
      for (int mi = 0; mi < 8; ++mi)
#pragma unroll
        for (int ni = 0; ni < 4; ++ni)
          acc_out[mi][ni] = __builtin_amdgcn_mfma_f32_16x16x32_f16(aw[mi], bh[ni], acc_out[mi][ni], 0, 0, 0);
    }
    __syncthreads();
  }

  // ---- 4: epilogue: + bo + residual, f32 out [b][o][p] ----
#pragma unroll
  for (int mi = 0; mi < 8; ++mi) {
#pragma unroll
    for (int j = 0; j < 4; ++j) {
      const int o = wm4 * 128 + mi * 16 + r4 + j;
      const float bov = bo[o];
      const long obase = (long)b * 8388608 + ((long)o << 14) + p0;
#pragma unroll
      for (int ni = 0; ni < 4; ++ni) {
        const int p = wn2 * 64 + ni * 16 + cl;
        out[obase + p] = acc_out[mi][ni][j] + bov + xr[obase + p];
      }
    }
  }
}

// ---------------------------------------------------------------------------
// launcher
// ---------------------------------------------------------------------------
extern "C" void kernel_launch(void* const* d_in, const int* in_sizes, int n_in,
                              void* d_out, int out_size, void* d_ws, size_t ws_size,
                              hipStream_t stream)
{
  (void)in_sizes; (void)n_in; (void)out_size; (void)ws_size;
  const float* x     = (const float*)d_in[0];
  const float* ctx   = (const float*)d_in[1];
  const float* gamma = (const float*)d_in[2];
  const float* beta  = (const float*)d_in[3];
  const float* wq    = (const float*)d_in[4];
  const float* bq    = (const float*)d_in[5];
  const float* wkv   = (const float*)d_in[6];
  const float* bkv   = (const float*)d_in[7];
  const float* wo    = (const float*)d_in[8];
  const float* bo    = (const float*)d_in[9];
  float* out = (float*)d_out;

  char* ws = (char*)d_ws;
  size_t off = 0;
  auto alloc = [&](size_t bytes) -> void* {
    void* p = ws + off;
    off += (bytes + 255) & ~(size_t)255;
    return p;
  };
  const long HPC = 8388608;                        // 16384*512 per batch
  _Float16* hF   = (_Float16*)alloc(2 * HPC * 2);  // h [b][p][c] f16
  _Float16* wqF  = (_Float16*)alloc(512 * 512 * 2);
  _Float16* woF  = (_Float16*)alloc(512 * 512 * 2);
  _Float16* kF   = (_Float16*)alloc(2 * 64 * 512 * 2);   // k [b][s][c]
  _Float16* vTF  = (_Float16*)alloc(2 * 512 * 64 * 2);   // vT [b][c][s]

  gn_fused<<<dim3(16, 32, 2), 256, 0, stream>>>(x, gamma, beta, hF);
  to_f16<<<dim3(256), 256, 0, stream>>>(wq, wqF, 65536);
  to_f16<<<dim3(256), 256, 0, stream>>>(wo, woF, 65536);
  kv_gemm<<<dim3(64, 2), 256, 0, stream>>>(ctx, wkv, bkv, kF, vTF);

  fused_qao<<<dim3(128, 2), 512, 0, stream>>>(
      hF, wqF, bq, kF, vTF, woF, bo, x, out);
}